// Round 16
// baseline (1276.873 us; speedup 1.0000x reference)
//
#include <hip/hip_runtime.h>
#include <cstdint>
#include <cstddef>

#define S_TOK 8192
#define MDIM  2048
#define NEXP  64
#define CAPTY 256
#define NCHUNK 128        // S_TOK / 64

#define CHUNK_BLOCKS 128  // one block per 64-token chunk: GEMM+gate+rank
#define FILL_BLOCKS 2048  // 2048 blocks x 256 thr x 128 float4 = 1.0737 GB

// ---------------------------------------------------------------------------
// Mega kernel. Blocks [0,128): per-chunk full-K logits GEMM (64x64 tile, LDS),
// then in-block softmax gating (lane=expert) and stable within-chunk ranking
// (wave 0, lane=token). Blocks [128, 2176): zero-fill the 1.074 GB output.
// The gating chain has no cross-block deps, so it all hides under the
// store-BW-bound fill (~183 us).
// ---------------------------------------------------------------------------
__global__ __launch_bounds__(256) void moe_mega(
    const float* __restrict__ x, const float* __restrict__ wg,
    const float* __restrict__ gum, float* __restrict__ out,
    int* __restrict__ e1o, int* __restrict__ e2o,
    float* __restrict__ g1o, float* __restrict__ g2o,
    int* __restrict__ w1, int* __restrict__ w2,
    int* __restrict__ hist1T, int* __restrict__ hist2T,   // [NEXP][NCHUNK]
    float* __restrict__ me_partT) {                        // [NEXP][NCHUNK]
  const int bid = blockIdx.x;
  const int t = threadIdx.x;

  if (bid >= CHUNK_BLOCKS) {
    // ---- zero-fill branch: 67,108,864 float4 total ----
    const int fb = bid - CHUNK_BLOCKS;  // 0..2047
    float4 z = {0.f, 0.f, 0.f, 0.f};
    float4* o4 = reinterpret_cast<float4*>(out);
    size_t idx = (size_t)fb * 256 + t;
#pragma unroll 8
    for (int i = 0; i < 128; ++i) {
      o4[idx] = z;
      idx += (size_t)FILL_BLOCKS * 256;
    }
    if (fb == 0 && t == 0) out[268435456] = 0.f;  // tail element (out_size-1)
    return;
  }

  // ---- chunk branch ----
  __shared__ float xs[64][36];
  __shared__ float wsh[64][36];
  __shared__ float lg[64][65];   // logits tile [token][expert], padded
  __shared__ float me_l[NEXP];
  __shared__ int e1_l[64], e2_l[64];
  __shared__ float g1_l[64], g2_l[64];

  const int c = bid;
  const int rowBase = c * 64;
  const int tx = t & 15;         // experts tx + 16*b
  const int ty = t >> 4;         // tokens ty*4 + a
  const int rStage = t >> 3;     // 0..31
  const int cStage = (t & 7) << 2;

  float acc[4][4] = {{0.f}};

  // -- K half 0: [0,1024) --
  for (int kt = 0; kt < 1024; kt += 32) {
    for (int rr = rStage; rr < 64; rr += 32) {
      *reinterpret_cast<float4*>(&xs[rr][cStage]) =
          *reinterpret_cast<const float4*>(
              &x[(size_t)(rowBase + rr) * MDIM + kt + cStage]);
      *reinterpret_cast<float4*>(&wsh[rr][cStage]) =
          *reinterpret_cast<const float4*>(
              &wg[(size_t)rr * MDIM + kt + cStage]);
    }
    __syncthreads();
#pragma unroll
    for (int k = 0; k < 32; k += 4) {
      float4 xa[4], wb[4];
#pragma unroll
      for (int a = 0; a < 4; ++a)
        xa[a] = *reinterpret_cast<const float4*>(&xs[ty * 4 + a][k]);
#pragma unroll
      for (int b = 0; b < 4; ++b)
        wb[b] = *reinterpret_cast<const float4*>(&wsh[tx + 16 * b][k]);
#pragma unroll
      for (int a = 0; a < 4; ++a)
#pragma unroll
        for (int b = 0; b < 4; ++b) {
          acc[a][b] += xa[a].x * wb[b].x;
          acc[a][b] += xa[a].y * wb[b].y;
          acc[a][b] += xa[a].z * wb[b].z;
          acc[a][b] += xa[a].w * wb[b].w;
        }
    }
    __syncthreads();
  }
  // stash half-0 partials in lg (each thread its own cells; no race)
#pragma unroll
  for (int a = 0; a < 4; ++a)
#pragma unroll
    for (int b = 0; b < 4; ++b) {
      lg[ty * 4 + a][tx + 16 * b] = acc[a][b];
      acc[a][b] = 0.f;
    }

  // -- K half 1: [1024,2048) --
  for (int kt = 1024; kt < 2048; kt += 32) {
    for (int rr = rStage; rr < 64; rr += 32) {
      *reinterpret_cast<float4*>(&xs[rr][cStage]) =
          *reinterpret_cast<const float4*>(
              &x[(size_t)(rowBase + rr) * MDIM + kt + cStage]);
      *reinterpret_cast<float4*>(&wsh[rr][cStage]) =
          *reinterpret_cast<const float4*>(
              &wg[(size_t)rr * MDIM + kt + cStage]);
    }
    __syncthreads();
#pragma unroll
    for (int k = 0; k < 32; k += 4) {
      float4 xa[4], wb[4];
#pragma unroll
      for (int a = 0; a < 4; ++a)
        xa[a] = *reinterpret_cast<const float4*>(&xs[ty * 4 + a][k]);
#pragma unroll
      for (int b = 0; b < 4; ++b)
        wb[b] = *reinterpret_cast<const float4*>(&wsh[tx + 16 * b][k]);
#pragma unroll
      for (int a = 0; a < 4; ++a)
#pragma unroll
        for (int b = 0; b < 4; ++b) {
          acc[a][b] += xa[a].x * wb[b].x;
          acc[a][b] += xa[a].y * wb[b].y;
          acc[a][b] += xa[a].z * wb[b].z;
          acc[a][b] += xa[a].w * wb[b].w;
        }
    }
    __syncthreads();
  }
  // l = half0 + half1  (bit-identical to the la+lb split that passed)
#pragma unroll
  for (int a = 0; a < 4; ++a)
#pragma unroll
    for (int b = 0; b < 4; ++b)
      lg[ty * 4 + a][tx + 16 * b] += acc[a][b];

  if (t < NEXP) me_l[t] = 0.f;
  __syncthreads();

  // ---- gating: 4 waves, wave wv handles tokens wv*16 .. wv*16+15 ----
  const int wv = t >> 6;
  const int lane = t & 63;
  float me_acc = 0.f;
#pragma unroll 1
  for (int i = 0; i < 16; ++i) {
    const int tok = wv * 16 + i;
    const int s = rowBase + tok;
    const float l = lg[tok][lane];
    const float gn = gum[(size_t)s * NEXP + lane];

    float m = l;
#pragma unroll
    for (int d = 1; d < 64; d <<= 1) m = fmaxf(m, __shfl_xor(m, d, 64));
    const float p = expf(l - m);
    float sum = p;
#pragma unroll
    for (int d = 1; d < 64; d <<= 1) sum += __shfl_xor(sum, d, 64);

    unsigned long long b1 = __ballot(l == m);
    const int e1 = __ffsll(b1) - 1;

    const float y = (lane == e1) ? -INFINITY : (l + gn);
    float m2 = y;
#pragma unroll
    for (int d = 1; d < 64; d <<= 1) m2 = fmaxf(m2, __shfl_xor(m2, d, 64));
    unsigned long long b2 = __ballot(y == m2);
    const int e2 = __ffsll(b2) - 1;

    const float p1 = __shfl(p, e1, 64);
    const float p2 = __shfl(p, e2, 64);

    me_acc += p / sum;  // softmax gate for (token s, expert lane)

    if (lane == 0) {
      e1_l[tok] = e1;
      e2_l[tok] = e2;
      g1_l[tok] = p1;
      g2_l[tok] = p2;
    }
  }
  atomicAdd(&me_l[lane], me_acc);
  __syncthreads();

  // coalesced per-chunk outputs
  if (t < 64) {
    e1o[rowBase + t] = e1_l[t];
    e2o[rowBase + t] = e2_l[t];
    g1o[rowBase + t] = g1_l[t];
    g2o[rowBase + t] = g2_l[t];
    me_partT[(size_t)t * NCHUNK + c] = me_l[t];
  }

  // ---- ranking: wave 0, lane = token within chunk ----
  if (wv == 0) {
    const int a = e1_l[lane];
    const int b = e2_l[lane];
    const unsigned long long lt = (1ull << lane) - 1ull;
    int r1 = 0, r2 = 0;
    for (int e = 0; e < NEXP; ++e) {
      unsigned long long m1 = __ballot(a == e);
      unsigned long long m2 = __ballot(b == e);
      if (a == e) r1 = __popcll(m1 & lt);
      if (b == e) r2 = __popcll(m2 & lt);
      if (lane == e) {
        hist1T[e * NCHUNK + c] = __popcll(m1);
        hist2T[e * NCHUNK + c] = __popcll(m2);
      }
    }
    w1[rowBase + lane] = r1;
    w2[rowBase + lane] = r2;
  }
}

// ---------------------------------------------------------------------------
// Prefix + l_aux: one wave; per expert e, shuffle-scan the 128 chunk counts
// (two 64-wide inclusive scans), coalesced transposed layout.
// ---------------------------------------------------------------------------
__global__ __launch_bounds__(64) void prefix_aux(
    const int* __restrict__ hist1T, const int* __restrict__ hist2T,
    const float* __restrict__ me_partT,
    int* __restrict__ off1T, int* __restrict__ off2T,
    float* __restrict__ out0) {
  const int lane = threadIdx.x;
  float la_acc = 0.f;
  for (int e = 0; e < NEXP; ++e) {
    const int h0 = hist1T[e * NCHUNK + lane];
    const int h1 = hist1T[e * NCHUNK + 64 + lane];
    int s0 = h0;
#pragma unroll
    for (int d = 1; d < 64; d <<= 1) {
      int v = __shfl_up(s0, d, 64);
      if (lane >= d) s0 += v;
    }
    const int tot0 = __shfl(s0, 63, 64);
    int s1 = h1;
#pragma unroll
    for (int d = 1; d < 64; d <<= 1) {
      int v = __shfl_up(s1, d, 64);
      if (lane >= d) s1 += v;
    }
    s1 += tot0;
    const int tot1 = __shfl(s1, 63, 64);  // pre-drop count1 -> ce*S and loc2 base
    off1T[e * NCHUNK + lane] = s0 - h0;
    off1T[e * NCHUNK + 64 + lane] = s1 - h1;

    const int h2a = hist2T[e * NCHUNK + lane];
    const int h2b = hist2T[e * NCHUNK + 64 + lane];
    int s2a = h2a;
#pragma unroll
    for (int d = 1; d < 64; d <<= 1) {
      int v = __shfl_up(s2a, d, 64);
      if (lane >= d) s2a += v;
    }
    const int tot2a = __shfl(s2a, 63, 64);
    int s2b = h2b;
#pragma unroll
    for (int d = 1; d < 64; d <<= 1) {
      int v = __shfl_up(s2b, d, 64);
      if (lane >= d) s2b += v;
    }
    off2T[e * NCHUNK + lane] = tot1 + s2a - h2a;
    off2T[e * NCHUNK + 64 + lane] = tot1 + tot2a + s2b - h2b;

    float ms = me_partT[e * NCHUNK + lane] + me_partT[e * NCHUNK + 64 + lane];
#pragma unroll
    for (int d = 1; d < 64; d <<= 1) ms += __shfl_xor(ms, d, 64);
    if (lane == 0) la_acc += ms * (float)tot1;
  }
  if (lane == 0)
    out0[0] = la_acc * (float)NEXP / ((float)S_TOK * (float)S_TOK);
}

// ---------------------------------------------------------------------------
// Scatter nonzeros into combine_weights / dispatch_mask.
// ---------------------------------------------------------------------------
__global__ __launch_bounds__(256) void scatter(
    const int* __restrict__ e1, const int* __restrict__ e2,
    const int* __restrict__ w1, const int* __restrict__ w2,
    const float* __restrict__ g1r, const float* __restrict__ g2r,
    const int* __restrict__ off1T, const int* __restrict__ off2T,
    float* __restrict__ out) {
  const int s = blockIdx.x * 256 + threadIdx.x;
  const int c = s >> 6;
  const int a = e1[s];
  const int b = e2[s];
  const int l1 = off1T[a * NCHUNK + c] + w1[s];
  const int l2 = off2T[b * NCHUNK + c] + w2[s];
  const bool k1 = l1 < CAPTY;
  const bool k2 = l2 < CAPTY;
  float p1 = k1 ? g1r[s] : 0.f;
  float p2 = k2 ? g2r[s] : 0.f;
  const float denom = p1 + p2;
  if (denom > 0.f) {
    const float inv = 1.f / denom;
    float* cw = out + 1;
    float* dm = out + 1 + (size_t)S_TOK * NEXP * CAPTY;
    const size_t rowb = (size_t)s * NEXP * CAPTY;
    if (k1) {
      const size_t i1 = rowb + (size_t)a * CAPTY + l1;
      cw[i1] = p1 * inv;
      dm[i1] = 1.f;
    }
    if (k2) {
      const size_t i2 = rowb + (size_t)b * CAPTY + l2;
      cw[i2] = p2 * inv;
      dm[i2] = 1.f;
    }
  }
}

// ---------------------------------------------------------------------------
extern "C" void kernel_launch(void* const* d_in, const int* in_sizes, int n_in,
                              void* d_out, int out_size, void* d_ws,
                              size_t ws_size, hipStream_t stream) {
  const float* x = (const float*)d_in[0];
  const float* wg = (const float*)d_in[1];
  const float* gum = (const float*)d_in[2];
  float* out = (float*)d_out;

  char* w = (char*)d_ws;
  size_t off = 0;
  int*   e1   = (int*)(w + off); off += (size_t)S_TOK * 4;
  int*   e2   = (int*)(w + off); off += (size_t)S_TOK * 4;
  float* g1r  = (float*)(w + off); off += (size_t)S_TOK * 4;
  float* g2r  = (float*)(w + off); off += (size_t)S_TOK * 4;
  int*   w1   = (int*)(w + off); off += (size_t)S_TOK * 4;
  int*   w2   = (int*)(w + off); off += (size_t)S_TOK * 4;
  int*   hist1T = (int*)(w + off); off += (size_t)NEXP * NCHUNK * 4;
  int*   hist2T = (int*)(w + off); off += (size_t)NEXP * NCHUNK * 4;
  int*   off1T  = (int*)(w + off); off += (size_t)NEXP * NCHUNK * 4;
  int*   off2T  = (int*)(w + off); off += (size_t)NEXP * NCHUNK * 4;
  float* me_partT = (float*)(w + off); off += (size_t)NEXP * NCHUNK * 4;

  moe_mega<<<CHUNK_BLOCKS + FILL_BLOCKS, 256, 0, stream>>>(
      x, wg, gum, out, e1, e2, g1r, g2r, w1, w2, hist1T, hist2T, me_partT);
  prefix_aux<<<1, 64, 0, stream>>>(hist1T, hist2T, me_partT, off1T, off2T,
                                   out);
  scatter<<<S_TOK / 256, 256, 0, stream>>>(e1, e2, w1, w2, g1r, g2r, off1T,
                                           off2T, out);
}